// Round 2
// baseline (66732.294 us; speedup 1.0000x reference)
//
#include <hip/hip_runtime.h>

// Stacked Clockwork RNN — persistent systolic-pipeline kernel (round 2).
// B=32, T=512, DIN=H=1024, DEPTH=4, col groups of 256 with periods 1,2,4,8.
// 256 WGs (1/CU): 64 WGs per depth, 16 cols each, weights resident in LDS.
// Tick r: depth d computes t = r - d. One two-level grid barrier per tick.

#define BB 32
#define TT 512
#define HH 1024
#define DEPTH 4
#define NTICK (TT + DEPTH - 1)          // 515
#define OUT_BSTR (TT * DEPTH * HH)      // out[b][t][d][c] b-stride (floats)
#define HPLANE (DEPTH * BB * HH)        // hbuf per-parity plane (floats)
#define BHH (BB * HH)
#define WH_OFF 16384                    // LDS float offset of Wh slabs
#define LDS_BYTES (2 * 16 * 1024 * 4)   // 128 KiB

// ---------------- grid barrier (two-level, monotonic counters) ----------------
__device__ __forceinline__ void gbarrier(unsigned* bar, int r, int xcd, int tid) {
  __syncthreads();                       // drains this WG's stores to L2
  if (tid == 0) {
    __threadfence();                     // agent release: writeback L2
    unsigned* cx = bar + 16 + 16 * xcd;  // 64B-spaced per-XCD-class lines
    unsigned old = __hip_atomic_fetch_add(cx, 1u, __ATOMIC_ACQ_REL, __HIP_MEMORY_SCOPE_AGENT);
    if (old == 32u * (unsigned)r - 1u) { // last of my class this tick
      __hip_atomic_fetch_add(bar, 1u, __ATOMIC_ACQ_REL, __HIP_MEMORY_SCOPE_AGENT);
    }
    while (__hip_atomic_load(bar, __ATOMIC_RELAXED, __HIP_MEMORY_SCOPE_AGENT) < 8u * (unsigned)r)
      __builtin_amdgcn_s_sleep(1);
    __threadfence();                     // agent acquire: invalidate stale caches
  }
  __syncthreads();
}

// ---------------- k-slice accumulate: acc[b] += sum_k in[b][k]*W[k][c] ----------------
// LDS slab layout per col: [ks*64 + (kk ^ (ks<<2) ^ ((cl&7)<<2))], kk < S.
__device__ __forceinline__ void accum_part(float acc[32], const float* __restrict__ wslab,
                                           int ks, int cl, const float* __restrict__ gin,
                                           size_t bstr, int S) {
  const int xswz = ((ks & 15) << 2) ^ ((cl & 7) << 2);
  for (int kb = 0; kb < S; kb += 16) {
    const float4 w0 = *(const float4*)(wslab + ks * 64 + ((kb +  0) ^ xswz));
    const float4 w1 = *(const float4*)(wslab + ks * 64 + ((kb +  4) ^ xswz));
    const float4 w2 = *(const float4*)(wslab + ks * 64 + ((kb +  8) ^ xswz));
    const float4 w3 = *(const float4*)(wslab + ks * 64 + ((kb + 12) ^ xswz));
    const float* p = gin + ks * S + kb;
#pragma unroll
    for (int b = 0; b < 32; ++b) {
      const float4 v0 = *(const float4*)(p + 0);
      const float4 v1 = *(const float4*)(p + 4);
      const float4 v2 = *(const float4*)(p + 8);
      const float4 v3 = *(const float4*)(p + 12);
      float a = acc[b];
      a = fmaf(v0.x, w0.x, a); a = fmaf(v0.y, w0.y, a); a = fmaf(v0.z, w0.z, a); a = fmaf(v0.w, w0.w, a);
      a = fmaf(v1.x, w1.x, a); a = fmaf(v1.y, w1.y, a); a = fmaf(v1.z, w1.z, a); a = fmaf(v1.w, w1.w, a);
      a = fmaf(v2.x, w2.x, a); a = fmaf(v2.y, w2.y, a); a = fmaf(v2.z, w2.z, a); a = fmaf(v2.w, w2.w, a);
      a = fmaf(v3.x, w3.x, a); a = fmaf(v3.y, w3.y, a); a = fmaf(v3.z, w3.z, a); a = fmaf(v3.w, w3.w, a);
      acc[b] = a;
      p += bstr;
    }
  }
}

__global__ __launch_bounds__(256) void cw_persistent(
    const float* __restrict__ x,     // [B][T][DIN]
    const float* __restrict__ wx0,   // [DIN][H]
    const float* __restrict__ wxd,   // [3][H][H]
    const float* __restrict__ wh,    // [4][H][H]
    const float* __restrict__ bias,  // [4][H]
    float* __restrict__ out,         // [B][T][4][H]
    float* __restrict__ hbuf,        // [2][4][B][H] (ws)
    unsigned* __restrict__ bar)      // barrier counters (ws)
{
  extern __shared__ float lds[];     // Wx slabs [16c][1024] + Wh slabs [16c][1024]

  const int bid = blockIdx.x;
  const int tid = threadIdx.x;
  const int xcd = bid & 7;           // barrier class (also likely-XCD for locality)
  const int d   = xcd >> 1;          // depth 0..3 pinned to an XCD pair
  const int idx = ((xcd & 1) << 5) | (bid >> 3);  // 0..63 col-group within depth
  const int c0  = idx << 4;          // 16 cols
  const int g   = c0 >> 8;           // clock group, period 2^g
  const int j0  = g << 8;            // recurrent sources j in [j0, 1024)
  const int Sh  = (HH - j0) >> 4;    // per-lane h k-slice: 64,48,32,16

  const float* wx_d = (d == 0) ? wx0 : (wxd + (size_t)(d - 1) * HH * HH);
  const float* wh_d = wh + (size_t)d * HH * HH;
  const float* bias_d = bias + d * HH;

  // ---- preload weight slabs into LDS (swizzled) ----
  {
    const int rr = tid >> 4, cl2 = tid & 15;
    const int cs = (cl2 & 7) << 2;
    for (int ks = 0; ks < 16; ++ks) {
#pragma unroll
      for (int kb = 0; kb < 64; kb += 16) {
        const int kk = kb + rr;
        lds[cl2 * 1024 + ks * 64 + (kk ^ (ks << 2) ^ cs)] =
            wx_d[(size_t)(ks * 64 + kk) * HH + c0 + cl2];
      }
    }
    for (int ks = 0; ks < 16; ++ks) {
      for (int kb = 0; kb < Sh; kb += 16) {
        const int kk = kb + rr;
        lds[WH_OFF + cl2 * 1024 + ks * 64 + (kk ^ (ks << 2) ^ cs)] =
            wh_d[(size_t)(j0 + ks * Sh + kk) * HH + c0 + cl2];
      }
    }
  }
  __syncthreads();

  const int ks = tid & 15;           // k-slice lane (low 4 lane bits)
  const int cl = tid >> 4;           // column within WG (wave = 4 cols x 16 ks)
  const int gc = c0 + cl;

  for (int r = 1; r <= NTICK; ++r) {
    const int t = r - d;
    if (t >= 1 && t <= TT) {
      float* hw = hbuf + (size_t)(t & 1) * HPLANE + (size_t)d * BHH;
      const float* hr = hbuf + (size_t)((t - 1) & 1) * HPLANE + (size_t)d * BHH;
      float* outp = out + (size_t)(t - 1) * (DEPTH * HH) + (size_t)d * HH;

      if ((t & ((1 << g) - 1)) == 0) {
        // ---------- active: pre = cur @ Wx + h[j0:] @ Wh + b; h = tanh(pre) ----------
        const float* cur; size_t cbstr;
        if (d == 0) { cur = x + (size_t)(t - 1) * HH; cbstr = (size_t)TT * HH; }
        else        { cur = hbuf + (size_t)(t & 1) * HPLANE + (size_t)(d - 1) * BHH; cbstr = HH; }

        float acc[32];
#pragma unroll
        for (int b = 0; b < 32; ++b) acc[b] = 0.f;

        accum_part(acc, lds + cl * 1024, ks, cl, cur, cbstr, 64);
        accum_part(acc, lds + WH_OFF + cl * 1024, ks, cl, hr + j0, HH, Sh);

        // ---- fold-reduce over 16 ks lanes: lane ks ends with b = 2ks, 2ks+1 ----
        float v16[16];
#pragma unroll
        for (int b = 0; b < 16; ++b) {
          const float keep = (ks & 8) ? acc[b + 16] : acc[b];
          const float give = (ks & 8) ? acc[b] : acc[b + 16];
          v16[b] = keep + __shfl_xor(give, 8);
        }
        float v8[8];
#pragma unroll
        for (int b = 0; b < 8; ++b) {
          const float keep = (ks & 4) ? v16[b + 8] : v16[b];
          const float give = (ks & 4) ? v16[b] : v16[b + 8];
          v8[b] = keep + __shfl_xor(give, 4);
        }
        float v4[4];
#pragma unroll
        for (int b = 0; b < 4; ++b) {
          const float keep = (ks & 2) ? v8[b + 4] : v8[b];
          const float give = (ks & 2) ? v8[b] : v8[b + 4];
          v4[b] = keep + __shfl_xor(give, 2);
        }
        float v2[2];
#pragma unroll
        for (int b = 0; b < 2; ++b) {
          const float keep = (ks & 1) ? v4[b + 2] : v4[b];
          const float give = (ks & 1) ? v4[b] : v4[b + 2];
          v2[b] = keep + __shfl_xor(give, 1);
        }

        const float bv = bias_d[gc];
        const int b0 = ks * 2;
        const float y0 = tanhf(v2[0] + bv);
        const float y1 = tanhf(v2[1] + bv);
        hw[(size_t)b0 * HH + gc] = y0;
        hw[(size_t)(b0 + 1) * HH + gc] = y1;
        outp[(size_t)b0 * OUT_BSTR + gc] = y0;
        outp[(size_t)(b0 + 1) * OUT_BSTR + gc] = y1;
      } else {
        // ---------- inactive: state copy-through ----------
#pragma unroll
        for (int i = 0; i < 2; ++i) {
          const int e = tid + i * 256;       // 0..511 = 32b x 16c
          const int b = e >> 4, cc = e & 15;
          const float v = hr[(size_t)b * HH + c0 + cc];
          hw[(size_t)b * HH + c0 + cc] = v;
          outp[(size_t)b * OUT_BSTR + c0 + cc] = v;
        }
      }
    }
    gbarrier(bar, r, xcd, tid);
  }
}

extern "C" void kernel_launch(void* const* d_in, const int* in_sizes, int n_in,
                              void* d_out, int out_size, void* d_ws, size_t ws_size,
                              hipStream_t stream) {
  const float* x    = (const float*)d_in[0];
  const float* Wx0  = (const float*)d_in[1];
  const float* Wxd  = (const float*)d_in[2];
  const float* Wh   = (const float*)d_in[3];
  const float* bias = (const float*)d_in[4];
  float* out = (float*)d_out;

  unsigned* bar = (unsigned*)d_ws;                       // 4 KiB barrier region
  float* hbuf = (float*)((char*)d_ws + 4096);            // [2][4][32][1024] floats

  // zero barrier counters + parity-0 state plane (h(0) = 0)
  hipMemsetAsync(d_ws, 0, 4096 + (size_t)HPLANE * sizeof(float), stream);

  (void)hipFuncSetAttribute((const void*)cw_persistent,
                            hipFuncAttributeMaxDynamicSharedMemorySize, LDS_BYTES);

  cw_persistent<<<256, 256, LDS_BYTES, stream>>>(x, Wx0, Wxd, Wh, bias, out, hbuf, bar);
}

// Round 3
// 40811.240 us; speedup vs baseline: 1.6351x; 1.6351x over previous
//
#include <hip/hip_runtime.h>

// Stacked Clockwork RNN — persistent kernel, round 3: fence-free coherence.
// 256 WGs (1/CU, LDS-bound). WG = (depth d = bid>>6, idx = bid&63) owns cols
// {256g + 4*idx .. +4 : g=0..3} — 4 cols per clock group => uniform load.
// Tick r: depth d computes t = r - d. Barrier: flag-store + master-poll +
// broadcast (no RMW chains, no release fences); consumers pay one acquire
// fence (buffer_inv) per tick; bulk reads are plain cached loads.

#define BB 32
#define TT 512
#define HH 1024
#define DEPTH 4
#define NTICK (TT + DEPTH - 1)          // 515
#define OUT_BSTR (TT * DEPTH * HH)      // out[b][t][d][c] b-stride (floats)
#define HPLANE (DEPTH * BB * HH)        // hbuf per-parity plane (floats)
#define BHH (BB * HH)
#define LDS_FLOATS 26624                // 64KB Wx + 40KB Wh = 104KB
#define LDS_BYTES (LDS_FLOATS * 4)

__device__ __forceinline__ float4 ld4(const float* p) { return *(const float4*)p; }

__device__ __forceinline__ void st_coh(float* p, float v) {
  __hip_atomic_store(p, v, __ATOMIC_RELAXED, __HIP_MEMORY_SCOPE_SYSTEM);
}

__global__ __launch_bounds__(256) void cw3(
    const float* __restrict__ x,     // [B][T][DIN]
    const float* __restrict__ wx0,   // [DIN][H]
    const float* __restrict__ wxd,   // [3][H][H]
    const float* __restrict__ wh,    // [4][H][H]
    const float* __restrict__ bias,  // [4][H]
    float* __restrict__ out,         // [B][T][4][H]
    float* __restrict__ hbuf,        // [2][4][B][H] (ws)
    unsigned* __restrict__ flags,    // 256 flags, 64B apart (ws)
    unsigned* __restrict__ bcast)    // release broadcast (ws)
{
  extern __shared__ float lds[];
  const int bid = blockIdx.x, tid = threadIdx.x;
  const int d = bid >> 6, idx = bid & 63;
  const float* wx_d = (d == 0) ? wx0 : (wxd + (size_t)(d - 1) * HH * HH);
  const float* wh_d = wh + (size_t)d * HH * HH;
  const float* bias_d = bias + d * HH;
  const int whoff[4] = {16384, 20480, 23552, 25600};

  // ---- one-time weight staging into LDS (linear k layout) ----
  {
    const int cc = tid & 3, kk = tid >> 2;
    for (int g = 0; g < 4; ++g) {
      const int cb = (g << 8) + (idx << 2);
      float* slab = lds + g * 4096;                     // [4c][1024k]
      for (int k0 = 0; k0 < 1024; k0 += 64)
        slab[cc * 1024 + k0 + kk] = wx_d[(size_t)(k0 + kk) * HH + cb + cc];
    }
    for (int g = 0; g < 4; ++g) {
      const int cb = (g << 8) + (idx << 2);
      const int Kh = 1024 - (g << 8);
      float* slab = lds + whoff[g];                     // [4c][Kh]
      for (int k0 = 0; k0 < Kh; k0 += 64)
        slab[cc * Kh + k0 + kk] = wh_d[(size_t)((g << 8) + k0 + kk) * HH + cb + cc];
    }
  }
  __syncthreads();

  const int ks = tid & 63;        // lane: 64-way k split (within wave)
  const int cl = tid >> 6;        // wave = which of the 4 cols of the tile
  const int koff = ks << 2;       // lane's float4 within each 256-float chunk

  for (int r = 1; r <= NTICK; ++r) {
    const int t = r - d;
    if (t >= 1 && t <= TT) {
      float* hw = hbuf + (size_t)(t & 1) * HPLANE + (size_t)d * BHH;
      const float* hr = hbuf + (size_t)((t - 1) & 1) * HPLANE + (size_t)d * BHH;
      const float* cur; int cstr;
      if (d == 0) { cur = x + (size_t)(t - 1) * HH; cstr = TT * HH; }
      else        { cur = hbuf + (size_t)(t & 1) * HPLANE + (size_t)(d - 1) * BHH; cstr = HH; }
      float* outp = out + (size_t)((t - 1) * DEPTH + d) * HH;

      for (int g = 0; g < 4; ++g) {
        const int cb = (g << 8) + (idx << 2);
        if ((t & ((1 << g) - 1)) == 0) {
          // ---------- active tile: 4 cols x 32 b, k split 64-way ----------
          float acc[32];
#pragma unroll
          for (int b = 0; b < 32; ++b) acc[b] = 0.f;

          const float* wxs = lds + g * 4096 + cl * 1024;
          for (int j = 0; j < 4; ++j) {                 // cur @ Wx (k=1024)
            const float4 w = ld4(wxs + j * 256 + koff);
            const float* vp = cur + j * 256 + koff;
#pragma unroll
            for (int b = 0; b < 32; ++b) {
              const float4 v = ld4(vp + (size_t)b * cstr);
              float a = acc[b];
              a = fmaf(v.x, w.x, a); a = fmaf(v.y, w.y, a);
              a = fmaf(v.z, w.z, a); a = fmaf(v.w, w.w, a);
              acc[b] = a;
            }
          }
          const int Kh = 1024 - (g << 8);
          const float* whs = lds + whoff[g] + cl * Kh;
          const float* hrg = hr + (g << 8);
          const int nj = 4 - g;
          for (int j = 0; j < nj; ++j) {                // h[j0:] @ Wh (masked)
            const float4 w = ld4(whs + j * 256 + koff);
            const float* vp = hrg + j * 256 + koff;
#pragma unroll
            for (int b = 0; b < 32; ++b) {
              const float4 v = ld4(vp + (size_t)b * HH);
              float a = acc[b];
              a = fmaf(v.x, w.x, a); a = fmaf(v.y, w.y, a);
              a = fmaf(v.z, w.z, a); a = fmaf(v.w, w.w, a);
              acc[b] = a;
            }
          }

          // ---- 6-round in-wave fold: 64 k-lanes x 32 accs -> b = ks>>1 ----
          float v16[16];
#pragma unroll
          for (int b = 0; b < 16; ++b) {
            const float keep = (ks & 32) ? acc[b + 16] : acc[b];
            const float give = (ks & 32) ? acc[b] : acc[b + 16];
            v16[b] = keep + __shfl_xor(give, 32);
          }
          float v8[8];
#pragma unroll
          for (int b = 0; b < 8; ++b) {
            const float keep = (ks & 16) ? v16[b + 8] : v16[b];
            const float give = (ks & 16) ? v16[b] : v16[b + 8];
            v8[b] = keep + __shfl_xor(give, 16);
          }
          float v4[4];
#pragma unroll
          for (int b = 0; b < 4; ++b) {
            const float keep = (ks & 8) ? v4[0] * 0.f + v8[b + 4] : v8[b];
            const float give = (ks & 8) ? v8[b] : v8[b + 4];
            v4[b] = keep + __shfl_xor(give, 8);
          }
          float v2[2];
#pragma unroll
          for (int b = 0; b < 2; ++b) {
            const float keep = (ks & 4) ? v4[b + 2] : v4[b];
            const float give = (ks & 4) ? v4[b] : v4[b + 2];
            v2[b] = keep + __shfl_xor(give, 4);
          }
          float v1;
          {
            const float keep = (ks & 2) ? v2[1] : v2[0];
            const float give = (ks & 2) ? v2[0] : v2[1];
            v1 = keep + __shfl_xor(give, 2);
          }
          v1 += __shfl_xor(v1, 1);

          if (!(ks & 1)) {
            const int b = ks >> 1;
            const int c = cb + cl;
            const float y = tanhf(v1 + bias_d[c]);
            st_coh(&hw[(size_t)b * HH + c], y);
            outp[(size_t)b * OUT_BSTR + c] = y;         // out: plain store
          }
        } else {
          // ---------- inactive tile: copy-through ----------
          if (tid < 128) {
            const int b = tid >> 2, c = cb + (tid & 3);
            const float v0 = hr[(size_t)b * HH + c];
            st_coh(&hw[(size_t)b * HH + c], v0);
            outp[(size_t)b * OUT_BSTR + c] = v0;
          }
        }
      }
    }

    // ---------------- fence-free grid barrier ----------------
    asm volatile("s_waitcnt vmcnt(0)" ::: "memory");    // own stores at coherence pt
    __syncthreads();                                    // all waves done
    if (bid == 0) {
      if (tid < 64) {
        if (tid == 0)
          __hip_atomic_store(&flags[0], (unsigned)r, __ATOMIC_RELAXED, __HIP_MEMORY_SCOPE_SYSTEM);
        const unsigned* fp = flags + tid * 16;          // 64B-spaced flags
        for (;;) {
          const unsigned a0 = __hip_atomic_load(fp,        __ATOMIC_RELAXED, __HIP_MEMORY_SCOPE_SYSTEM);
          const unsigned a1 = __hip_atomic_load(fp + 1024, __ATOMIC_RELAXED, __HIP_MEMORY_SCOPE_SYSTEM);
          const unsigned a2 = __hip_atomic_load(fp + 2048, __ATOMIC_RELAXED, __HIP_MEMORY_SCOPE_SYSTEM);
          const unsigned a3 = __hip_atomic_load(fp + 3072, __ATOMIC_RELAXED, __HIP_MEMORY_SCOPE_SYSTEM);
          const int ok = (a0 >= (unsigned)r) && (a1 >= (unsigned)r) &&
                         (a2 >= (unsigned)r) && (a3 >= (unsigned)r);
          if (__all(ok)) break;
          __builtin_amdgcn_s_sleep(2);
        }
        if (tid == 0)
          __hip_atomic_store(bcast, (unsigned)r, __ATOMIC_RELAXED, __HIP_MEMORY_SCOPE_SYSTEM);
      }
    } else if (tid == 0) {
      __hip_atomic_store(&flags[bid * 16], (unsigned)r, __ATOMIC_RELAXED, __HIP_MEMORY_SCOPE_SYSTEM);
      while (__hip_atomic_load(bcast, __ATOMIC_RELAXED, __HIP_MEMORY_SCOPE_SYSTEM) < (unsigned)r)
        __builtin_amdgcn_s_sleep(2);
    }
    if (tid == 0)
      __builtin_amdgcn_fence(__ATOMIC_ACQUIRE, "agent"); // buffer_inv only — no wbl2
    __syncthreads();
  }
}

extern "C" void kernel_launch(void* const* d_in, const int* in_sizes, int n_in,
                              void* d_out, int out_size, void* d_ws, size_t ws_size,
                              hipStream_t stream) {
  const float* x    = (const float*)d_in[0];
  const float* Wx0  = (const float*)d_in[1];
  const float* Wxd  = (const float*)d_in[2];
  const float* Wh   = (const float*)d_in[3];
  const float* bias = (const float*)d_in[4];
  float* out = (float*)d_out;

  unsigned* flags = (unsigned*)d_ws;                      // 16 KiB (256 x 64B)
  unsigned* bcast = (unsigned*)((char*)d_ws + 16384);     // 1 line
  float* hbuf = (float*)((char*)d_ws + 32768);            // [2][4][32][1024]

  // zero flags + bcast + parity-0 state plane (h0 = 0)
  hipMemsetAsync(d_ws, 0, 32768 + (size_t)HPLANE * sizeof(float), stream);

  (void)hipFuncSetAttribute((const void*)cw3,
                            hipFuncAttributeMaxDynamicSharedMemorySize, LDS_BYTES);

  cw3<<<256, 256, LDS_BYTES, stream>>>(x, Wx0, Wxd, Wh, bias, out, hbuf, flags, bcast);
}

// Round 7
// 8306.001 us; speedup vs baseline: 8.0342x; 4.9135x over previous
//
#include <hip/hip_runtime.h>

// Stacked Clockwork RNN — persistent kernel, round 4 design (4th submit; three
// infra timeouts, never executed).
// 256 WGs x 512 thr. WG(d = bid>>6, idx = bid&63) owns cols {256g+4idx..+3}.
// Weights in LDS (104 KiB). Cross-WG state: write-through system stores +
// system-scope bypass loads (IFC-coherent) => NO cache-maintenance fences.
// Tick r: depth d computes t = r-d. Flag barrier, master-poll, no fences.

#define BB 32
#define TT 512
#define HH 1024
#define DEPTH 4
#define NTICK (TT + DEPTH - 1)          // 515
#define OUT_BSTR (TT * DEPTH * HH)      // out[b][t][d][c] b-stride (floats)
#define HPLANE (DEPTH * BB * HH)        // hbuf per-parity plane (floats)
#define BHH (BB * HH)
#define LDS_FLOATS 26624                // 16c x 1024 Wx + masked Wh = 104 KiB
#define LDS_BYTES (LDS_FLOATS * 4)

__device__ __forceinline__ void st_coh(float* p, float v) {
  __hip_atomic_store(p, v, __ATOMIC_RELAXED, __HIP_MEMORY_SCOPE_SYSTEM);
}
__device__ __forceinline__ float ld_coh(const float* p) {
  return __hip_atomic_load(p, __ATOMIC_RELAXED, __HIP_MEMORY_SCOPE_SYSTEM);
}
__device__ __forceinline__ void ld8_coh(const float* p, float& a, float& b) {
  union { unsigned long long u; float f[2]; } cv;
  cv.u = __hip_atomic_load((const unsigned long long*)p, __ATOMIC_RELAXED,
                           __HIP_MEMORY_SCOPE_SYSTEM);
  a = cv.f[0]; b = cv.f[1];
}

// ---- load/FMA building blocks (bb,g,ci unrolled => acc statically indexed) ----
#define LOADC(R, j) do { \
  if (d == 0) { \
    _Pragma("unroll") for (int bb = 0; bb < 4; ++bb) \
      R[bb] = *(const float4*)(xb + (size_t)(b0+bb)*(size_t)(TT*HH) + (j)*256 + (l<<2)); \
  } else { \
    _Pragma("unroll") for (int bb = 0; bb < 4; ++bb) { \
      const float* p_ = curh + (size_t)(b0+bb)*HH + (j)*256 + (l<<2); \
      ld8_coh(p_, R[bb].x, R[bb].y); ld8_coh(p_+2, R[bb].z, R[bb].w); } \
  } } while(0)

#define LOADH(R, j) do { \
  _Pragma("unroll") for (int bb = 0; bb < 4; ++bb) { \
    const float* p_ = hr + (size_t)(b0+bb)*HH + (j)*256 + (l<<2); \
    ld8_coh(p_, R[bb].x, R[bb].y); ld8_coh(p_+2, R[bb].z, R[bb].w); } } while(0)

#define FMAC(R, j) do { \
  _Pragma("unroll") for (int g = 0; g < 4; ++g) if ((actm >> g) & 1) { \
    _Pragma("unroll") for (int ci = 0; ci < 4; ++ci) { \
      const float4 w = *(const float4*)(lds + ((g<<2)|ci)*1024 + (j)*256 + (l<<2)); \
      _Pragma("unroll") for (int bb = 0; bb < 4; ++bb) { \
        float a = acc[(bb<<4)|(g<<2)|ci]; \
        a = fmaf(R[bb].x, w.x, a); a = fmaf(R[bb].y, w.y, a); \
        a = fmaf(R[bb].z, w.z, a); a = fmaf(R[bb].w, w.w, a); \
        acc[(bb<<4)|(g<<2)|ci] = a; } } } } while(0)

#define FMAH(R, j) do { \
  _Pragma("unroll") for (int g = 0; g < 4; ++g) if (g <= (j) && ((actm >> g) & 1)) { \
    const int whb_ = 16384 + 4608*g - 512*g*g; \
    const int Lg_ = 1024 - (g<<8); \
    _Pragma("unroll") for (int ci = 0; ci < 4; ++ci) { \
      const float4 w = *(const float4*)(lds + whb_ + ci*Lg_ + ((j)-g)*256 + (l<<2)); \
      _Pragma("unroll") for (int bb = 0; bb < 4; ++bb) { \
        float a = acc[(bb<<4)|(g<<2)|ci]; \
        a = fmaf(R[bb].x, w.x, a); a = fmaf(R[bb].y, w.y, a); \
        a = fmaf(R[bb].z, w.z, a); a = fmaf(R[bb].w, w.w, a); \
        acc[(bb<<4)|(g<<2)|ci] = a; } } } } while(0)

__global__ __launch_bounds__(512, 2) void cw4(
    const float* __restrict__ x,     // [B][T][DIN]
    const float* __restrict__ wx0,   // [DIN][H]
    const float* __restrict__ wxd,   // [3][H][H]
    const float* __restrict__ wh,    // [4][H][H]
    const float* __restrict__ bias,  // [4][H]
    float* __restrict__ out,         // [B][T][4][H]
    float* __restrict__ hbuf,        // [2][4][B][H] (ws)
    unsigned* __restrict__ flags,    // 256 flags, 64B apart (ws)
    unsigned* __restrict__ bcast)    // release broadcast (ws)
{
  extern __shared__ float lds[];
  const int bid = blockIdx.x, tid = threadIdx.x;
  const int d = bid >> 6, idx = bid & 63;
  const float* wx_d = (d == 0) ? wx0 : (wxd + (size_t)(d - 1) * HH * HH);
  const float* wh_d = wh + (size_t)d * HH * HH;
  const float* bias_d = bias + d * HH;

  // ---- one-time weight staging into LDS ----
  {
    const int cc = tid & 15, k0 = tid >> 4;          // 16 cols x 32 k-stripes
    const int g = cc >> 2;
    const int gc = (g << 8) + (idx << 2) + (cc & 3);
    for (int kk = k0; kk < 1024; kk += 32)
      lds[cc * 1024 + kk] = wx_d[(size_t)kk * HH + gc];
    const int whb = 16384 + 4608 * g - 512 * g * g;
    const int Lg = 1024 - (g << 8);
    for (int kk = k0; kk < Lg; kk += 32)
      lds[whb + (cc & 3) * Lg + kk] = wh_d[(size_t)((g << 8) + kk) * HH + gc];
  }
  __syncthreads();

  const int l = tid & 63;            // lane
  const int b0 = (tid >> 6) << 2;    // wave's batch slice base (4 b)
  // output-lane mapping: lane l -> (b = b0 + (l>>4), col = l&15)
  const int occ = l & 15, og = occ >> 2;
  const int oc = (og << 8) + (idx << 2) + (occ & 3);
  const int ob = b0 + (l >> 4);
  const float bias_v = bias_d[oc];

#pragma unroll 1
  for (int r = 1; r <= NTICK; ++r) {
    const int t = r - d;
    if (t >= 1 && t <= TT) {
      float* hw = hbuf + (size_t)(t & 1) * HPLANE + (size_t)d * BHH;
      const float* hr = hbuf + (size_t)((t - 1) & 1) * HPLANE + (size_t)d * BHH;
      const float* curh = hbuf + (size_t)(t & 1) * HPLANE + (size_t)(d - 1) * BHH;
      const float* xb = x + (size_t)(t - 1) * HH;
      float* outt = out + (size_t)((t - 1) * DEPTH + d) * HH;
      const int actm = 1 | ((!(t & 1)) << 1) | ((!(t & 3)) << 2) | ((!(t & 7)) << 3);

      float acc[64];
#pragma unroll
      for (int i = 0; i < 64; ++i) acc[i] = 0.f;

      float4 A[4], Bv[4];
      LOADC(A, 0);
#pragma unroll 1
      for (int j = 0; j < 4; j += 2) {       // cur @ Wx sweep (k = 1024)
        LOADC(Bv, j + 1);
        FMAC(A, j);
        if (j < 2) { LOADC(A, j + 2); } else { LOADH(A, 0); }
        FMAC(Bv, j + 1);
      }
#pragma unroll 1
      for (int j = 0; j < 4; j += 2) {       // h[mask] @ Wh sweep
        LOADH(Bv, j + 1);
        FMAH(A, j);
        if (j < 2) LOADH(A, j + 2);
        FMAH(Bv, j + 1);
      }

      // ---- 6-round fold: lane l ends with output index l = (bb<<4)|cc ----
      float v32[32];
#pragma unroll
      for (int i = 0; i < 32; ++i) {
        const float lo = acc[i], up = acc[i + 32];
        const float keep = (l & 32) ? up : lo, give = (l & 32) ? lo : up;
        v32[i] = keep + __shfl_xor(give, 32);
      }
      float v16[16];
#pragma unroll
      for (int i = 0; i < 16; ++i) {
        const float lo = v32[i], up = v32[i + 16];
        const float keep = (l & 16) ? up : lo, give = (l & 16) ? lo : up;
        v16[i] = keep + __shfl_xor(give, 16);
      }
      float v8[8];
#pragma unroll
      for (int i = 0; i < 8; ++i) {
        const float lo = v16[i], up = v16[i + 8];
        const float keep = (l & 8) ? up : lo, give = (l & 8) ? lo : up;
        v8[i] = keep + __shfl_xor(give, 8);
      }
      float v4[4];
#pragma unroll
      for (int i = 0; i < 4; ++i) {
        const float lo = v8[i], up = v8[i + 4];
        const float keep = (l & 4) ? up : lo, give = (l & 4) ? lo : up;
        v4[i] = keep + __shfl_xor(give, 4);
      }
      float v2[2];
#pragma unroll
      for (int i = 0; i < 2; ++i) {
        const float lo = v4[i], up = v4[i + 2];
        const float keep = (l & 2) ? up : lo, give = (l & 2) ? lo : up;
        v2[i] = keep + __shfl_xor(give, 2);
      }
      float v1;
      {
        const float lo = v2[0], up = v2[1];
        const float keep = (l & 1) ? up : lo, give = (l & 1) ? lo : up;
        v1 = keep + __shfl_xor(give, 1);
      }

      // ---- outputs: active -> tanh result; inactive -> copy-through ----
      float* hwp = hw + (size_t)ob * HH + oc;
      float* outp = outt + (size_t)ob * OUT_BSTR + oc;
      if ((actm >> og) & 1) {
        const float y = tanhf(v1 + bias_v);
        st_coh(hwp, y);
        *outp = y;
      } else {
        const float v0 = ld_coh(hr + (size_t)ob * HH + oc);
        st_coh(hwp, v0);
        *outp = v0;
      }
    }

    // ---------------- zero-fence grid barrier ----------------
    asm volatile("s_waitcnt vmcnt(0)" ::: "memory");   // sc1 stores at coherence pt
    __syncthreads();
    if (bid == 0) {
      if (tid < 64) {
        if (tid == 0)
          __hip_atomic_store(&flags[0], (unsigned)r, __ATOMIC_RELAXED, __HIP_MEMORY_SCOPE_SYSTEM);
        const unsigned* fp = flags + tid * 16;
        for (;;) {
          const unsigned a0 = __hip_atomic_load(fp,        __ATOMIC_RELAXED, __HIP_MEMORY_SCOPE_SYSTEM);
          const unsigned a1 = __hip_atomic_load(fp + 1024, __ATOMIC_RELAXED, __HIP_MEMORY_SCOPE_SYSTEM);
          const unsigned a2 = __hip_atomic_load(fp + 2048, __ATOMIC_RELAXED, __HIP_MEMORY_SCOPE_SYSTEM);
          const unsigned a3 = __hip_atomic_load(fp + 3072, __ATOMIC_RELAXED, __HIP_MEMORY_SCOPE_SYSTEM);
          const int ok = (a0 >= (unsigned)r) && (a1 >= (unsigned)r) &&
                         (a2 >= (unsigned)r) && (a3 >= (unsigned)r);
          if (__all(ok)) break;
          __builtin_amdgcn_s_sleep(1);
        }
        if (tid == 0)
          __hip_atomic_store(bcast, (unsigned)r, __ATOMIC_RELAXED, __HIP_MEMORY_SCOPE_SYSTEM);
      }
    } else if (tid == 0) {
      __hip_atomic_store(&flags[bid * 16], (unsigned)r, __ATOMIC_RELAXED, __HIP_MEMORY_SCOPE_SYSTEM);
      while (__hip_atomic_load(bcast, __ATOMIC_RELAXED, __HIP_MEMORY_SCOPE_SYSTEM) < (unsigned)r)
        __builtin_amdgcn_s_sleep(1);
    }
    __syncthreads();
  }
}

extern "C" void kernel_launch(void* const* d_in, const int* in_sizes, int n_in,
                              void* d_out, int out_size, void* d_ws, size_t ws_size,
                              hipStream_t stream) {
  const float* x    = (const float*)d_in[0];
  const float* Wx0  = (const float*)d_in[1];
  const float* Wxd  = (const float*)d_in[2];
  const float* Wh   = (const float*)d_in[3];
  const float* bias = (const float*)d_in[4];
  float* out = (float*)d_out;

  unsigned* flags = (unsigned*)d_ws;                      // 16 KiB (256 x 64B)
  unsigned* bcast = (unsigned*)((char*)d_ws + 16384);
  float* hbuf = (float*)((char*)d_ws + 32768);            // [2][4][32][1024]

  // zero flags + bcast + parity-0 state plane (h0 = 0)
  hipMemsetAsync(d_ws, 0, 32768 + (size_t)HPLANE * sizeof(float), stream);

  (void)hipFuncSetAttribute((const void*)cw4,
                            hipFuncAttributeMaxDynamicSharedMemorySize, LDS_BYTES);

  cw4<<<256, 512, LDS_BYTES, stream>>>(x, Wx0, Wxd, Wh, bias, out, hbuf, flags, bcast);
}